// Round 13
// baseline (149.351 us; speedup 1.0000x reference)
//
#include <hip/hip_runtime.h>
#include <hip/hip_bf16.h>

// KascadeReuseAttention  B=1, S=2048, DM=1024, H=16, D=64, T=16, NA=3
// Round-29 (base r27 = 144.7us). r28 setprio REGRESSED (+1.4us):
// uniform-program waves -> elevating the body phase starves newly
// arrived waves' load prologues. setprio joins DPP on the attn ban
// list; reverted. This round: attn launched as 4096 blocks x 512
// threads (8 waves/block, was 8192x256). Per-wave program unchanged
// (w8 slice indexing only); occupancy still 32 waves/CU (LDS 6.5KB,
// 4 blocks/CU); halves block dispatch count on the 35us kernel.
// All else frozen: prep (r25), qkv BK=64 (r27), out BK=64 (r27).
// History: r18/r22 attn regressions (VGPR-40 collapse; DPP banned),
// r20 qkv dbuf +1.3, r21 XCD remap ~0, r25 prep retile + out dbuf
// -3.5, r26 counted-vmcnt -1.1, r27 BK=64 -0.7, r28 setprio +1.4
// (reverted).
// Budget: ~45us ws-poison fill (immovable) + ~35 attn + ~16-18 qkv +
// ~6 prep + ~6 out + gaps.

#define S_LEN 2048
#define DM 1024
#define NH 16
#define HD 64

typedef __bf16 bf16x8 __attribute__((ext_vector_type(8)));
typedef float f32x4 __attribute__((ext_vector_type(4)));

static __device__ __forceinline__ unsigned short f2bf(float f) {
    union { float f; unsigned int i; } un;
    un.f = f;
    unsigned int r = un.i + 0x7FFFu + ((un.i >> 16) & 1u);  // RNE
    return (unsigned short)(r >> 16);
}
static __device__ __forceinline__ float bfu2f(unsigned short u) {
    union { unsigned int i; float f; } un;
    un.i = ((unsigned int)u) << 16;
    return un.f;
}
static __device__ __forceinline__ float bflo(unsigned int u) {
    union { unsigned int i; float f; } un;
    un.i = u << 16;
    return un.f;
}
static __device__ __forceinline__ float bfhi(unsigned int u) {
    union { unsigned int i; float f; } un;
    un.i = u & 0xFFFF0000u;
    return un.f;
}

// async global->LDS, 16 B per lane; LDS dest = uniform base + lane*16.
static __device__ __forceinline__ void gll16(const unsigned short* g,
                                             unsigned short* l) {
    __builtin_amdgcn_global_load_lds(
        (const __attribute__((address_space(1))) unsigned int*)(uintptr_t)g,
        (__attribute__((address_space(3))) unsigned int*)(uintptr_t)l,
        16, 0, 0);
}

// ---------------------------------------------------------------------------
// prep (r25-verbatim): blocks [0,1024) transpose W* fp32->bf16 [n][k] in
// 64x64 tiles (LDS [64][65]); blocks [1024,2048) convert x fp32->bf16.
// ---------------------------------------------------------------------------
__global__ __launch_bounds__(256) void prep(
    const float* __restrict__ x, unsigned short* __restrict__ xb,
    const float* __restrict__ W0, const float* __restrict__ W1,
    const float* __restrict__ W2, const float* __restrict__ W3,
    unsigned short* __restrict__ T0, unsigned short* __restrict__ T1,
    unsigned short* __restrict__ T2, unsigned short* __restrict__ T3) {
    const int bx = blockIdx.x;
    if (bx < 1024) {
        const int z = bx >> 8, rem = bx & 255;
        const float* W = (z == 0) ? W0 : (z == 1) ? W1 : (z == 2) ? W2 : W3;
        unsigned short* T = (z == 0) ? T0 : (z == 1) ? T1 : (z == 2) ? T2 : T3;
        __shared__ float t[64][65];
        const int bn = (rem & 15) * 64, bk = (rem >> 4) * 64;
        const int tx = threadIdx.x & 63, ty = threadIdx.x >> 6;  // ty 0..3
        #pragma unroll
        for (int m = 0; m < 16; ++m)            // 64 k-rows, 256B reads
            t[ty + m * 4][tx] = W[(size_t)(bk + ty + m * 4) * 1024 + bn + tx];
        __syncthreads();
        #pragma unroll
        for (int m = 0; m < 16; ++m)            // 64 n-rows, 128B writes
            T[(size_t)(bn + ty + m * 4) * 1024 + bk + tx] =
                f2bf(t[tx][ty + m * 4]);
    } else {
        const int i = (bx - 1024) * 2048 + threadIdx.x * 8;
        float4 f0 = *(const float4*)(x + i);
        float4 f1 = *(const float4*)(x + i + 4);
        ushort4 o0, o1;
        o0.x = f2bf(f0.x); o0.y = f2bf(f0.y); o0.z = f2bf(f0.z); o0.w = f2bf(f0.w);
        o1.x = f2bf(f1.x); o1.y = f2bf(f1.y); o1.z = f2bf(f1.z); o1.w = f2bf(f1.w);
        *(ushort4*)(xb + i) = o0;
        *(ushort4*)(xb + i + 4) = o1;
    }
}

// ---------------------------------------------------------------------------
// QKV GEMM (r27-verbatim): 64x128 tile, BK=64, grid (24,32) = 768 blocks
// (3/CU), GLL width-16 staging, 2-buffer stage-ahead, one barrier per
// iter (16 iters). Fused RoPE epilogue, head-major bf16 out [H][S][64].
// ---------------------------------------------------------------------------
__global__ __launch_bounds__(256) void gemm_qkv(
    const unsigned short* __restrict__ xb,
    const unsigned short* __restrict__ Wtq, const unsigned short* __restrict__ Wtk,
    const unsigned short* __restrict__ Wtv,
    unsigned short* __restrict__ qh, unsigned short* __restrict__ kh,
    unsigned short* __restrict__ vh,
    const float* __restrict__ cs, const float* __restrict__ sn) {
    __shared__ __align__(16) unsigned short Al[2][64 * 64];
    __shared__ __align__(16) unsigned short Bl[2][128 * 64];
    const int tid = threadIdx.x;
    const int nb = blockIdx.x >> 3;
    const unsigned short* __restrict__ Bt = (nb == 0) ? Wtq : (nb == 1) ? Wtk : Wtv;
    unsigned short* __restrict__ OUT = (nb == 0) ? qh : (nb == 1) ? kh : vh;
    const int col0 = (blockIdx.x & 7) * 128;
    const int row0 = blockIdx.y * 64;
    const int lane = tid & 63, wvi = tid >> 6;
    const int wr = (wvi >> 1) * 32, wc = (wvi & 1) * 64;
    const int l15 = lane & 15, quad = lane >> 4;

    // BK=64 staging: 8 lanes per 128B row, 8 rows per gll16 call.
    const int grow8 = lane >> 3;           // 0..7
    const int gkc8 = (lane & 7) * 8;       // element offset within row
    const unsigned short* gA = xb + (size_t)(row0 + wvi * 16 + grow8) * 1024 + gkc8;
    const unsigned short* gB = Bt + (size_t)(col0 + wvi * 32 + grow8) * 1024 + gkc8;
    const int lAo = (wvi * 16) * 64;       // wave-uniform offsets in a buffer
    const int lBo = (wvi * 32) * 64;

    f32x4 acc[2][4] = {};
    // prologue: stage tile 0 into buf 0 (A: 2 calls, B: 4 calls per wave)
    gll16(gA, Al[0] + lAo);
    gll16(gA + 8 * 1024, Al[0] + lAo + 8 * 64);
    gll16(gB, Bl[0] + lBo);
    gll16(gB + 8 * 1024, Bl[0] + lBo + 8 * 64);
    gll16(gB + 16 * 1024, Bl[0] + lBo + 16 * 64);
    gll16(gB + 24 * 1024, Bl[0] + lBo + 24 * 64);
    __syncthreads();
    for (int it = 0; it < 16; ++it) {
        const int cur = it & 1;
        if (it < 15) {                      // issue next-tile loads first
            const int k1 = (it + 1) * 64;
            const int nx = cur ^ 1;
            gll16(gA + k1, Al[nx] + lAo);
            gll16(gA + 8 * 1024 + k1, Al[nx] + lAo + 8 * 64);
            gll16(gB + k1, Bl[nx] + lBo);
            gll16(gB + 8 * 1024 + k1, Bl[nx] + lBo + 8 * 64);
            gll16(gB + 16 * 1024 + k1, Bl[nx] + lBo + 16 * 64);
            gll16(gB + 24 * 1024 + k1, Bl[nx] + lBo + 24 * 64);
        }
        #pragma unroll
        for (int ks = 0; ks < 2; ++ks) {
            bf16x8 af[2], bfr[4];
            #pragma unroll
            for (int i = 0; i < 2; ++i)
                af[i] = *(const bf16x8*)
                    &Al[cur][(wr + i * 16 + l15) * 64 + ks * 32 + quad * 8];
            #pragma unroll
            for (int j = 0; j < 4; ++j)
                bfr[j] = *(const bf16x8*)
                    &Bl[cur][(wc + j * 16 + l15) * 64 + ks * 32 + quad * 8];
            #pragma unroll
            for (int i = 0; i < 2; ++i)
                #pragma unroll
                for (int j = 0; j < 4; ++j)
                    acc[i][j] = __builtin_amdgcn_mfma_f32_16x16x32_bf16(
                        af[i], bfr[j], acc[i][j], 0, 0, 0);
        }
        __syncthreads();   // drains next-tile GLLs (flew under 2x compute)
    }

    // epilogue: wave's 64 cols = one head; fused RoPE; head-major store
    const int hh = ((blockIdx.x & 7) << 1) + (wc >> 6);
    const bool dorope = (nb != 2);
    #pragma unroll
    for (int i = 0; i < 2; ++i) {
        const int rowb = row0 + wr + i * 16 + quad * 4;
        #pragma unroll
        for (int r = 0; r < 4; ++r) {
            const int s = rowb + r;
            float v0 = acc[i][0][r], v1 = acc[i][1][r];
            float v2 = acc[i][2][r], v3 = acc[i][3][r];
            if (dorope) {
                float c0 = cs[s * 32 + l15],      s0 = sn[s * 32 + l15];
                float c1 = cs[s * 32 + 16 + l15], s1 = sn[s * 32 + 16 + l15];
                float lo0 = v0 * c0 - v2 * s0;
                float hi0 = v2 * c0 + v0 * s0;
                float lo1 = v1 * c1 - v3 * s1;
                float hi1 = v3 * c1 + v1 * s1;
                v0 = lo0; v1 = lo1; v2 = hi0; v3 = hi1;
            }
            unsigned short* op = OUT + (size_t)hh * (S_LEN * 64) + (size_t)s * 64 + l15;
            op[0]  = f2bf(v0);
            op[16] = f2bf(v1);
            op[32] = f2bf(v2);
            op[48] = f2bf(v3);
        }
    }
}

// ---------------------------------------------------------------------------
// Attention (r29): r21 per-wave program verbatim; launched as 4096
// blocks x 512 threads (8 waves/block). XCD-aware bijective remap:
// xcd=bid&7 owns heads {2*xcd, 2*xcd+1}; 256 q-blocks of 8 per head.
// ---------------------------------------------------------------------------
__global__ __launch_bounds__(512) void attn_kernel(
    const unsigned short* __restrict__ qh, const unsigned short* __restrict__ kh,
    const unsigned short* __restrict__ vh, const int* __restrict__ anc,
    unsigned short* __restrict__ att) {
    __shared__ __align__(16) float qs[8][64];
    __shared__ __align__(16) int   ts[8][64];
    __shared__ __align__(16) float ws[8][64];
    const int w8 = threadIdx.x >> 6;           // 0..7
    const int lane = threadIdx.x & 63;
    // XCD-aware remap (bijective over 4096 blocks x 8 waves = 32768).
    const int bid = blockIdx.x;
    const int xcd = bid & 7;
    const int idx = bid >> 3;                  // 0..511
    const int h   = (xcd << 1) | (idx >> 8);   // 2 heads per XCD
    const int qi  = ((idx & 255) << 3) + w8;   // 256 q-blocks per head
    const size_t hb = (size_t)h * (S_LEN * 64);

    const float q_own = bfu2f(qh[hb + (size_t)qi * 64 + lane]);
    const int slot = lane >> 4;
    const int tile = (slot < 3) ? anc[((size_t)h * S_LEN + qi) * 3 + slot]
                                : (qi >> 4);
    const int tok_own = tile * 16 + (lane & 15);
    qs[w8][lane] = q_own;
    ts[w8][lane] = tok_own;

    const int c = lane & 3;
    const int t = lane >> 2;
    float qv[16];
    #pragma unroll
    for (int r = 0; r < 4; ++r) {
        float4 f = *(const float4*)&qs[w8][c * 16 + r * 4];
        qv[r * 4 + 0] = f.x; qv[r * 4 + 1] = f.y;
        qv[r * 4 + 2] = f.z; qv[r * 4 + 3] = f.w;
    }

    #pragma unroll
    for (int p = 0; p < 4; ++p) {
        const int tk = ts[w8][p * 16 + t];
        const unsigned short* kp = kh + hb + (size_t)tk * 64 + c * 16;
        const uint4 k0 = *(const uint4*)kp;
        const uint4 k1 = *(const uint4*)(kp + 8);
        float part;
        part = bflo(k0.x) * qv[0];
        part = fmaf(bfhi(k0.x), qv[1], part);
        part = fmaf(bflo(k0.y), qv[2], part);
        part = fmaf(bfhi(k0.y), qv[3], part);
        part = fmaf(bflo(k0.z), qv[4], part);
        part = fmaf(bfhi(k0.z), qv[5], part);
        part = fmaf(bflo(k0.w), qv[6], part);
        part = fmaf(bfhi(k0.w), qv[7], part);
        part = fmaf(bflo(k1.x), qv[8], part);
        part = fmaf(bfhi(k1.x), qv[9], part);
        part = fmaf(bflo(k1.y), qv[10], part);
        part = fmaf(bfhi(k1.y), qv[11], part);
        part = fmaf(bflo(k1.z), qv[12], part);
        part = fmaf(bfhi(k1.z), qv[13], part);
        part = fmaf(bflo(k1.w), qv[14], part);
        part = fmaf(bfhi(k1.w), qv[15], part);
        part += __shfl_xor(part, 1, 64);
        part += __shfl_xor(part, 2, 64);
        if (c == 0) ws[w8][p * 16 + t] = part;
    }

    float logit = ws[w8][lane];
    const bool fut = tok_own > qi;
    logit = fut ? -1e30f : logit * 0.125f;

    float m = logit;
    #pragma unroll
    for (int off = 32; off >= 1; off >>= 1)
        m = fmaxf(m, __shfl_xor(m, off, 64));
    const float e = fut ? 0.f : __expf(logit - m);
    float ssum = e;
    #pragma unroll
    for (int off = 32; off >= 1; off >>= 1)
        ssum += __shfl_xor(ssum, off, 64);
    ws[w8][lane] = e / ssum;

    // phase 4: vectorized weighted V sum.
    // lane -> (tq = token quad 0..3, dd = dim quad 0..15); round r covers
    // tokens r*4 .. r*4+3; each lane loads 4 bf16 dims (uint2, 8B).
    const int tq = lane >> 4;
    const int dd = lane & 15;
    const unsigned short* vbase = vh + hb + dd * 4;
    float a0 = 0.f, a1 = 0.f, a2 = 0.f, a3 = 0.f;
    #pragma unroll
    for (int r = 0; r < 16; ++r) {
        const int kk = r * 4 + tq;
        const int tok = ts[w8][kk];
        const uint2 vv = *(const uint2*)(vbase + (size_t)tok * 64);
        const float w = ws[w8][kk];
        a0 = fmaf(w, bflo(vv.x), a0);
        a1 = fmaf(w, bfhi(vv.x), a1);
        a2 = fmaf(w, bflo(vv.y), a2);
        a3 = fmaf(w, bfhi(vv.y), a3);
    }
    a0 += __shfl_xor(a0, 16, 64); a0 += __shfl_xor(a0, 32, 64);
    a1 += __shfl_xor(a1, 16, 64); a1 += __shfl_xor(a1, 32, 64);
    a2 += __shfl_xor(a2, 16, 64); a2 += __shfl_xor(a2, 32, 64);
    a3 += __shfl_xor(a3, 16, 64); a3 += __shfl_xor(a3, 32, 64);
    if (tq == 0) {
        ushort4 o;
        o.x = f2bf(a0); o.y = f2bf(a1); o.z = f2bf(a2); o.w = f2bf(a3);
        *(ushort4*)&att[(size_t)qi * DM + h * HD + dd * 4] = o;
    }
}

// ---------------------------------------------------------------------------
// Out GEMM (r27-verbatim): 64x64 tile, BK=64, grid (16,32) = 512 blocks
// = 2/CU, 2-buffer stage-ahead, one barrier per iter (16 iters).
// ---------------------------------------------------------------------------
__global__ __launch_bounds__(256) void gemm_out(
    const unsigned short* __restrict__ A, const unsigned short* __restrict__ Bt,
    float* __restrict__ C) {
    __shared__ __align__(16) unsigned short Al[2][64 * 64];
    __shared__ __align__(16) unsigned short Bl[2][64 * 64];
    const int tid = threadIdx.x;
    const int col0 = blockIdx.x * 64;
    const int row0 = blockIdx.y * 64;
    const int lane = tid & 63, wvi = tid >> 6;
    const int wr = (wvi >> 1) * 32, wc = (wvi & 1) * 32;
    const int l15 = lane & 15, quad = lane >> 4;

    const int grow8 = lane >> 3;
    const int gkc8 = (lane & 7) * 8;
    const unsigned short* gA = A + (size_t)(row0 + wvi * 16 + grow8) * 1024 + gkc8;
    const unsigned short* gB = Bt + (size_t)(col0 + wvi * 16 + grow8) * 1024 + gkc8;
    const int lAo = (wvi * 16) * 64;       // wave-uniform offsets in a buffer
    const int lBo = (wvi * 16) * 64;

    f32x4 acc[2][2] = {};
    // prologue: stage tile 0 into buf 0 (2 calls each for A and B)
    gll16(gA, Al[0] + lAo);
    gll16(gA + 8 * 1024, Al[0] + lAo + 8 * 64);
    gll16(gB, Bl[0] + lBo);
    gll16(gB + 8 * 1024, Bl[0] + lBo + 8 * 64);
    __syncthreads();
    for (int it = 0; it < 16; ++it) {
        const int cur = it & 1;
        if (it < 15) {                      // issue next-tile loads first
            const int k1 = (it + 1) * 64;
            const int nx = cur ^ 1;
            gll16(gA + k1, Al[nx] + lAo);
            gll16(gA + 8 * 1024 + k1, Al[nx] + lAo + 8 * 64);
            gll16(gB + k1, Bl[nx] + lBo);
            gll16(gB + 8 * 1024 + k1, Bl[nx] + lBo + 8 * 64);
        }
        #pragma unroll
        for (int ks = 0; ks < 2; ++ks) {
            bf16x8 af[2], bfr[2];
            #pragma unroll
            for (int i = 0; i < 2; ++i)
                af[i] = *(const bf16x8*)
                    &Al[cur][(wr + i * 16 + l15) * 64 + ks * 32 + quad * 8];
            #pragma unroll
            for (int j = 0; j < 2; ++j)
                bfr[j] = *(const bf16x8*)
                    &Bl[cur][(wc + j * 16 + l15) * 64 + ks * 32 + quad * 8];
            #pragma unroll
            for (int i = 0; i < 2; ++i)
                #pragma unroll
                for (int j = 0; j < 2; ++j)
                    acc[i][j] = __builtin_amdgcn_mfma_f32_16x16x32_bf16(
                        af[i], bfr[j], acc[i][j], 0, 0, 0);
        }
        __syncthreads();
    }
    #pragma unroll
    for (int i = 0; i < 2; ++i) {
        const int rowb = row0 + wr + i * 16 + quad * 4;
        #pragma unroll
        for (int r = 0; r < 4; ++r) {
            float* crow = C + (size_t)(rowb + r) * 1024 + col0 + wc;
            #pragma unroll
            for (int j = 0; j < 2; ++j)
                crow[j * 16 + l15] = acc[i][j][r];
        }
    }
}

// ---------------------------------------------------------------------------
extern "C" void kernel_launch(void* const* d_in, const int* in_sizes, int n_in,
                              void* d_out, int out_size, void* d_ws, size_t ws_size,
                              hipStream_t stream) {
    const float* x   = (const float*)d_in[0];
    const float* Wq  = (const float*)d_in[1];
    const float* Wk  = (const float*)d_in[2];
    const float* Wv  = (const float*)d_in[3];
    const float* Wo  = (const float*)d_in[4];
    const float* cs  = (const float*)d_in[5];
    const float* sn  = (const float*)d_in[6];
    const int*   anc = (const int*)d_in[7];
    float* out = (float*)d_out;

    unsigned short* xb  = (unsigned short*)d_ws;
    unsigned short* Wtq = xb  + (size_t)2048 * 1024;
    unsigned short* Wtk = Wtq + (size_t)1024 * 1024;
    unsigned short* Wtv = Wtk + (size_t)1024 * 1024;
    unsigned short* Wto = Wtv + (size_t)1024 * 1024;
    unsigned short* qh  = Wto + (size_t)1024 * 1024;   // [H][S][64]
    unsigned short* kh  = qh  + (size_t)2048 * 1024;
    unsigned short* vh  = kh  + (size_t)2048 * 1024;
    unsigned short* att = vh  + (size_t)2048 * 1024;   // [S][H*D]

    prep<<<2048, 256, 0, stream>>>(x, xb, Wq, Wk, Wv, Wo, Wtq, Wtk, Wtv, Wto);
    gemm_qkv<<<dim3(24, 32), 256, 0, stream>>>(xb, Wtq, Wtk, Wtv,
                                               qh, kh, vh, cs, sn);
    attn_kernel<<<4096, 512, 0, stream>>>(qh, kh, vh, anc, att);
    gemm_out<<<dim3(16, 32), 256, 0, stream>>>(att, Wto, out);
}

// Round 14
// 144.827 us; speedup vs baseline: 1.0312x; 1.0312x over previous
//
#include <hip/hip_runtime.h>
#include <hip/hip_bf16.h>

// KascadeReuseAttention  B=1, S=2048, DM=1024, H=16, D=64, T=16, NA=3
// Round-30 = r27 restored verbatim (best-known state, 144.7us).
// r28 (setprio) +1.4 and r29 (512-thread attn blocks) +4.6 both
// REGRESSED and are reverted. Attn ban list: DPP builtins, setprio,
// non-256 block shapes, LDS-anchor removal — all perturb the fragile
// high-ILP compiler schedule (fingerprint: VGPR 40, VALUBusy ~30%).
// Config: prep 64x64 retile (r25); qkv 64x128/BK=64 2-buf stage-ahead
// (r27); attn r21 (XCD head remap, 8192x256); out 64x64/BK=64 2-buf
// (r27).
// History: r20 qkv dbuf +1.3, r21 XCD remap ~0, r25 prep retile + out
// dbuf -3.5, r26 counted-vmcnt -1.1, r27 BK=64 -0.7.
// Budget: ~45us ws-poison fill + harness memsets (immovable) + ~35 attn
// + ~16-18 qkv + ~6 prep + ~6 out + gaps.

#define S_LEN 2048
#define DM 1024
#define NH 16
#define HD 64

typedef __bf16 bf16x8 __attribute__((ext_vector_type(8)));
typedef float f32x4 __attribute__((ext_vector_type(4)));

static __device__ __forceinline__ unsigned short f2bf(float f) {
    union { float f; unsigned int i; } un;
    un.f = f;
    unsigned int r = un.i + 0x7FFFu + ((un.i >> 16) & 1u);  // RNE
    return (unsigned short)(r >> 16);
}
static __device__ __forceinline__ float bfu2f(unsigned short u) {
    union { unsigned int i; float f; } un;
    un.i = ((unsigned int)u) << 16;
    return un.f;
}
static __device__ __forceinline__ float bflo(unsigned int u) {
    union { unsigned int i; float f; } un;
    un.i = u << 16;
    return un.f;
}
static __device__ __forceinline__ float bfhi(unsigned int u) {
    union { unsigned int i; float f; } un;
    un.i = u & 0xFFFF0000u;
    return un.f;
}

// async global->LDS, 16 B per lane; LDS dest = uniform base + lane*16.
static __device__ __forceinline__ void gll16(const unsigned short* g,
                                             unsigned short* l) {
    __builtin_amdgcn_global_load_lds(
        (const __attribute__((address_space(1))) unsigned int*)(uintptr_t)g,
        (__attribute__((address_space(3))) unsigned int*)(uintptr_t)l,
        16, 0, 0);
}

// ---------------------------------------------------------------------------
// prep (r25): blocks [0,1024) transpose W* fp32->bf16 [n][k] in 64x64
// tiles (LDS [64][65]); blocks [1024,2048) convert x fp32->bf16.
// ---------------------------------------------------------------------------
__global__ __launch_bounds__(256) void prep(
    const float* __restrict__ x, unsigned short* __restrict__ xb,
    const float* __restrict__ W0, const float* __restrict__ W1,
    const float* __restrict__ W2, const float* __restrict__ W3,
    unsigned short* __restrict__ T0, unsigned short* __restrict__ T1,
    unsigned short* __restrict__ T2, unsigned short* __restrict__ T3) {
    const int bx = blockIdx.x;
    if (bx < 1024) {
        const int z = bx >> 8, rem = bx & 255;
        const float* W = (z == 0) ? W0 : (z == 1) ? W1 : (z == 2) ? W2 : W3;
        unsigned short* T = (z == 0) ? T0 : (z == 1) ? T1 : (z == 2) ? T2 : T3;
        __shared__ float t[64][65];
        const int bn = (rem & 15) * 64, bk = (rem >> 4) * 64;
        const int tx = threadIdx.x & 63, ty = threadIdx.x >> 6;  // ty 0..3
        #pragma unroll
        for (int m = 0; m < 16; ++m)            // 64 k-rows, 256B reads
            t[ty + m * 4][tx] = W[(size_t)(bk + ty + m * 4) * 1024 + bn + tx];
        __syncthreads();
        #pragma unroll
        for (int m = 0; m < 16; ++m)            // 64 n-rows, 128B writes
            T[(size_t)(bn + ty + m * 4) * 1024 + bk + tx] =
                f2bf(t[tx][ty + m * 4]);
    } else {
        const int i = (bx - 1024) * 2048 + threadIdx.x * 8;
        float4 f0 = *(const float4*)(x + i);
        float4 f1 = *(const float4*)(x + i + 4);
        ushort4 o0, o1;
        o0.x = f2bf(f0.x); o0.y = f2bf(f0.y); o0.z = f2bf(f0.z); o0.w = f2bf(f0.w);
        o1.x = f2bf(f1.x); o1.y = f2bf(f1.y); o1.z = f2bf(f1.z); o1.w = f2bf(f1.w);
        *(ushort4*)(xb + i) = o0;
        *(ushort4*)(xb + i + 4) = o1;
    }
}

// ---------------------------------------------------------------------------
// QKV GEMM (r27): 64x128 tile, BK=64, grid (24,32) = 768 blocks (3/CU),
// GLL width-16 staging, 2-buffer stage-ahead, one barrier per iter (16
// iters). Fused RoPE epilogue, head-major bf16 out [H][S][64].
// ---------------------------------------------------------------------------
__global__ __launch_bounds__(256) void gemm_qkv(
    const unsigned short* __restrict__ xb,
    const unsigned short* __restrict__ Wtq, const unsigned short* __restrict__ Wtk,
    const unsigned short* __restrict__ Wtv,
    unsigned short* __restrict__ qh, unsigned short* __restrict__ kh,
    unsigned short* __restrict__ vh,
    const float* __restrict__ cs, const float* __restrict__ sn) {
    __shared__ __align__(16) unsigned short Al[2][64 * 64];
    __shared__ __align__(16) unsigned short Bl[2][128 * 64];
    const int tid = threadIdx.x;
    const int nb = blockIdx.x >> 3;
    const unsigned short* __restrict__ Bt = (nb == 0) ? Wtq : (nb == 1) ? Wtk : Wtv;
    unsigned short* __restrict__ OUT = (nb == 0) ? qh : (nb == 1) ? kh : vh;
    const int col0 = (blockIdx.x & 7) * 128;
    const int row0 = blockIdx.y * 64;
    const int lane = tid & 63, wvi = tid >> 6;
    const int wr = (wvi >> 1) * 32, wc = (wvi & 1) * 64;
    const int l15 = lane & 15, quad = lane >> 4;

    // BK=64 staging: 8 lanes per 128B row, 8 rows per gll16 call.
    const int grow8 = lane >> 3;           // 0..7
    const int gkc8 = (lane & 7) * 8;       // element offset within row
    const unsigned short* gA = xb + (size_t)(row0 + wvi * 16 + grow8) * 1024 + gkc8;
    const unsigned short* gB = Bt + (size_t)(col0 + wvi * 32 + grow8) * 1024 + gkc8;
    const int lAo = (wvi * 16) * 64;       // wave-uniform offsets in a buffer
    const int lBo = (wvi * 32) * 64;

    f32x4 acc[2][4] = {};
    // prologue: stage tile 0 into buf 0 (A: 2 calls, B: 4 calls per wave)
    gll16(gA, Al[0] + lAo);
    gll16(gA + 8 * 1024, Al[0] + lAo + 8 * 64);
    gll16(gB, Bl[0] + lBo);
    gll16(gB + 8 * 1024, Bl[0] + lBo + 8 * 64);
    gll16(gB + 16 * 1024, Bl[0] + lBo + 16 * 64);
    gll16(gB + 24 * 1024, Bl[0] + lBo + 24 * 64);
    __syncthreads();
    for (int it = 0; it < 16; ++it) {
        const int cur = it & 1;
        if (it < 15) {                      // issue next-tile loads first
            const int k1 = (it + 1) * 64;
            const int nx = cur ^ 1;
            gll16(gA + k1, Al[nx] + lAo);
            gll16(gA + 8 * 1024 + k1, Al[nx] + lAo + 8 * 64);
            gll16(gB + k1, Bl[nx] + lBo);
            gll16(gB + 8 * 1024 + k1, Bl[nx] + lBo + 8 * 64);
            gll16(gB + 16 * 1024 + k1, Bl[nx] + lBo + 16 * 64);
            gll16(gB + 24 * 1024 + k1, Bl[nx] + lBo + 24 * 64);
        }
        #pragma unroll
        for (int ks = 0; ks < 2; ++ks) {
            bf16x8 af[2], bfr[4];
            #pragma unroll
            for (int i = 0; i < 2; ++i)
                af[i] = *(const bf16x8*)
                    &Al[cur][(wr + i * 16 + l15) * 64 + ks * 32 + quad * 8];
            #pragma unroll
            for (int j = 0; j < 4; ++j)
                bfr[j] = *(const bf16x8*)
                    &Bl[cur][(wc + j * 16 + l15) * 64 + ks * 32 + quad * 8];
            #pragma unroll
            for (int i = 0; i < 2; ++i)
                #pragma unroll
                for (int j = 0; j < 4; ++j)
                    acc[i][j] = __builtin_amdgcn_mfma_f32_16x16x32_bf16(
                        af[i], bfr[j], acc[i][j], 0, 0, 0);
        }
        __syncthreads();   // drains next-tile GLLs (flew under 2x compute)
    }

    // epilogue: wave's 64 cols = one head; fused RoPE; head-major store
    const int hh = ((blockIdx.x & 7) << 1) + (wc >> 6);
    const bool dorope = (nb != 2);
    #pragma unroll
    for (int i = 0; i < 2; ++i) {
        const int rowb = row0 + wr + i * 16 + quad * 4;
        #pragma unroll
        for (int r = 0; r < 4; ++r) {
            const int s = rowb + r;
            float v0 = acc[i][0][r], v1 = acc[i][1][r];
            float v2 = acc[i][2][r], v3 = acc[i][3][r];
            if (dorope) {
                float c0 = cs[s * 32 + l15],      s0 = sn[s * 32 + l15];
                float c1 = cs[s * 32 + 16 + l15], s1 = sn[s * 32 + 16 + l15];
                float lo0 = v0 * c0 - v2 * s0;
                float hi0 = v2 * c0 + v0 * s0;
                float lo1 = v1 * c1 - v3 * s1;
                float hi1 = v3 * c1 + v1 * s1;
                v0 = lo0; v1 = lo1; v2 = hi0; v3 = hi1;
            }
            unsigned short* op = OUT + (size_t)hh * (S_LEN * 64) + (size_t)s * 64 + l15;
            op[0]  = f2bf(v0);
            op[16] = f2bf(v1);
            op[32] = f2bf(v2);
            op[48] = f2bf(v3);
        }
    }
}

// ---------------------------------------------------------------------------
// Attention (r21-verbatim, FROZEN): one wave per (h,q); XCD-aware head
// remap; wave-private LDS slices; same-address broadcast ds_reads;
// phase-4 vectorized V gather (uint2 x16) with addresses from ts.
// ---------------------------------------------------------------------------
__global__ __launch_bounds__(256) void attn_kernel(
    const unsigned short* __restrict__ qh, const unsigned short* __restrict__ kh,
    const unsigned short* __restrict__ vh, const int* __restrict__ anc,
    unsigned short* __restrict__ att) {
    __shared__ __align__(16) float qs[4][64];
    __shared__ __align__(16) int   ts[4][64];
    __shared__ __align__(16) float ws[4][64];
    const int w4 = threadIdx.x >> 6;
    const int lane = threadIdx.x & 63;
    // XCD-aware remap (bijective over 8192 blocks): each XCD owns 2 heads.
    const int bid = blockIdx.x;
    const int xcd = bid & 7;
    const int idx = bid >> 3;                  // 0..1023
    const int h   = (xcd << 1) | (idx >> 9);   // 2 heads per XCD
    const int qi  = ((idx & 511) << 2) + w4;   // 512 q-blocks per head
    const size_t hb = (size_t)h * (S_LEN * 64);

    const float q_own = bfu2f(qh[hb + (size_t)qi * 64 + lane]);
    const int slot = lane >> 4;
    const int tile = (slot < 3) ? anc[((size_t)h * S_LEN + qi) * 3 + slot]
                                : (qi >> 4);
    const int tok_own = tile * 16 + (lane & 15);
    qs[w4][lane] = q_own;
    ts[w4][lane] = tok_own;

    const int c = lane & 3;
    const int t = lane >> 2;
    float qv[16];
    #pragma unroll
    for (int r = 0; r < 4; ++r) {
        float4 f = *(const float4*)&qs[w4][c * 16 + r * 4];
        qv[r * 4 + 0] = f.x; qv[r * 4 + 1] = f.y;
        qv[r * 4 + 2] = f.z; qv[r * 4 + 3] = f.w;
    }

    #pragma unroll
    for (int p = 0; p < 4; ++p) {
        const int tk = ts[w4][p * 16 + t];
        const unsigned short* kp = kh + hb + (size_t)tk * 64 + c * 16;
        const uint4 k0 = *(const uint4*)kp;
        const uint4 k1 = *(const uint4*)(kp + 8);
        float part;
        part = bflo(k0.x) * qv[0];
        part = fmaf(bfhi(k0.x), qv[1], part);
        part = fmaf(bflo(k0.y), qv[2], part);
        part = fmaf(bfhi(k0.y), qv[3], part);
        part = fmaf(bflo(k0.z), qv[4], part);
        part = fmaf(bfhi(k0.z), qv[5], part);
        part = fmaf(bflo(k0.w), qv[6], part);
        part = fmaf(bfhi(k0.w), qv[7], part);
        part = fmaf(bflo(k1.x), qv[8], part);
        part = fmaf(bfhi(k1.x), qv[9], part);
        part = fmaf(bflo(k1.y), qv[10], part);
        part = fmaf(bfhi(k1.y), qv[11], part);
        part = fmaf(bflo(k1.z), qv[12], part);
        part = fmaf(bfhi(k1.z), qv[13], part);
        part = fmaf(bflo(k1.w), qv[14], part);
        part = fmaf(bfhi(k1.w), qv[15], part);
        part += __shfl_xor(part, 1, 64);
        part += __shfl_xor(part, 2, 64);
        if (c == 0) ws[w4][p * 16 + t] = part;
    }

    float logit = ws[w4][lane];
    const bool fut = tok_own > qi;
    logit = fut ? -1e30f : logit * 0.125f;

    float m = logit;
    #pragma unroll
    for (int off = 32; off >= 1; off >>= 1)
        m = fmaxf(m, __shfl_xor(m, off, 64));
    const float e = fut ? 0.f : __expf(logit - m);
    float ssum = e;
    #pragma unroll
    for (int off = 32; off >= 1; off >>= 1)
        ssum += __shfl_xor(ssum, off, 64);
    ws[w4][lane] = e / ssum;

    // phase 4: vectorized weighted V sum.
    // lane -> (tq = token quad 0..3, dd = dim quad 0..15); round r covers
    // tokens r*4 .. r*4+3; each lane loads 4 bf16 dims (uint2, 8B).
    const int tq = lane >> 4;
    const int dd = lane & 15;
    const unsigned short* vbase = vh + hb + dd * 4;
    float a0 = 0.f, a1 = 0.f, a2 = 0.f, a3 = 0.f;
    #pragma unroll
    for (int r = 0; r < 16; ++r) {
        const int kk = r * 4 + tq;
        const int tok = ts[w4][kk];
        const uint2 vv = *(const uint2*)(vbase + (size_t)tok * 64);
        const float w = ws[w4][kk];
        a0 = fmaf(w, bflo(vv.x), a0);
        a1 = fmaf(w, bfhi(vv.x), a1);
        a2 = fmaf(w, bflo(vv.y), a2);
        a3 = fmaf(w, bfhi(vv.y), a3);
    }
    a0 += __shfl_xor(a0, 16, 64); a0 += __shfl_xor(a0, 32, 64);
    a1 += __shfl_xor(a1, 16, 64); a1 += __shfl_xor(a1, 32, 64);
    a2 += __shfl_xor(a2, 16, 64); a2 += __shfl_xor(a2, 32, 64);
    a3 += __shfl_xor(a3, 16, 64); a3 += __shfl_xor(a3, 32, 64);
    if (tq == 0) {
        ushort4 o;
        o.x = f2bf(a0); o.y = f2bf(a1); o.z = f2bf(a2); o.w = f2bf(a3);
        *(ushort4*)&att[(size_t)qi * DM + h * HD + dd * 4] = o;
    }
}

// ---------------------------------------------------------------------------
// Out GEMM (r27): 64x64 tile, BK=64, grid (16,32) = 512 blocks = 2/CU,
// 2-buffer stage-ahead, one barrier per iter (16 iters). Wave tile 32x32.
// ---------------------------------------------------------------------------
__global__ __launch_bounds__(256) void gemm_out(
    const unsigned short* __restrict__ A, const unsigned short* __restrict__ Bt,
    float* __restrict__ C) {
    __shared__ __align__(16) unsigned short Al[2][64 * 64];
    __shared__ __align__(16) unsigned short Bl[2][64 * 64];
    const int tid = threadIdx.x;
    const int col0 = blockIdx.x * 64;
    const int row0 = blockIdx.y * 64;
    const int lane = tid & 63, wvi = tid >> 6;
    const int wr = (wvi >> 1) * 32, wc = (wvi & 1) * 32;
    const int l15 = lane & 15, quad = lane >> 4;

    const int grow8 = lane >> 3;
    const int gkc8 = (lane & 7) * 8;
    const unsigned short* gA = A + (size_t)(row0 + wvi * 16 + grow8) * 1024 + gkc8;
    const unsigned short* gB = Bt + (size_t)(col0 + wvi * 16 + grow8) * 1024 + gkc8;
    const int lAo = (wvi * 16) * 64;       // wave-uniform offsets in a buffer
    const int lBo = (wvi * 16) * 64;

    f32x4 acc[2][2] = {};
    // prologue: stage tile 0 into buf 0 (2 calls each for A and B)
    gll16(gA, Al[0] + lAo);
    gll16(gA + 8 * 1024, Al[0] + lAo + 8 * 64);
    gll16(gB, Bl[0] + lBo);
    gll16(gB + 8 * 1024, Bl[0] + lBo + 8 * 64);
    __syncthreads();
    for (int it = 0; it < 16; ++it) {
        const int cur = it & 1;
        if (it < 15) {                      // issue next-tile loads first
            const int k1 = (it + 1) * 64;
            const int nx = cur ^ 1;
            gll16(gA + k1, Al[nx] + lAo);
            gll16(gA + 8 * 1024 + k1, Al[nx] + lAo + 8 * 64);
            gll16(gB + k1, Bl[nx] + lBo);
            gll16(gB + 8 * 1024 + k1, Bl[nx] + lBo + 8 * 64);
        }
        #pragma unroll
        for (int ks = 0; ks < 2; ++ks) {
            bf16x8 af[2], bfr[2];
            #pragma unroll
            for (int i = 0; i < 2; ++i)
                af[i] = *(const bf16x8*)
                    &Al[cur][(wr + i * 16 + l15) * 64 + ks * 32 + quad * 8];
            #pragma unroll
            for (int j = 0; j < 2; ++j)
                bfr[j] = *(const bf16x8*)
                    &Bl[cur][(wc + j * 16 + l15) * 64 + ks * 32 + quad * 8];
            #pragma unroll
            for (int i = 0; i < 2; ++i)
                #pragma unroll
                for (int j = 0; j < 2; ++j)
                    acc[i][j] = __builtin_amdgcn_mfma_f32_16x16x32_bf16(
                        af[i], bfr[j], acc[i][j], 0, 0, 0);
        }
        __syncthreads();
    }
    #pragma unroll
    for (int i = 0; i < 2; ++i) {
        const int rowb = row0 + wr + i * 16 + quad * 4;
        #pragma unroll
        for (int r = 0; r < 4; ++r) {
            float* crow = C + (size_t)(rowb + r) * 1024 + col0 + wc;
            #pragma unroll
            for (int j = 0; j < 2; ++j)
                crow[j * 16 + l15] = acc[i][j][r];
        }
    }
}

// ---------------------------------------------------------------------------
extern "C" void kernel_launch(void* const* d_in, const int* in_sizes, int n_in,
                              void* d_out, int out_size, void* d_ws, size_t ws_size,
                              hipStream_t stream) {
    const float* x   = (const float*)d_in[0];
    const float* Wq  = (const float*)d_in[1];
    const float* Wk  = (const float*)d_in[2];
    const float* Wv  = (const float*)d_in[3];
    const float* Wo  = (const float*)d_in[4];
    const float* cs  = (const float*)d_in[5];
    const float* sn  = (const float*)d_in[6];
    const int*   anc = (const int*)d_in[7];
    float* out = (float*)d_out;

    unsigned short* xb  = (unsigned short*)d_ws;
    unsigned short* Wtq = xb  + (size_t)2048 * 1024;
    unsigned short* Wtk = Wtq + (size_t)1024 * 1024;
    unsigned short* Wtv = Wtk + (size_t)1024 * 1024;
    unsigned short* Wto = Wtv + (size_t)1024 * 1024;
    unsigned short* qh  = Wto + (size_t)1024 * 1024;   // [H][S][64]
    unsigned short* kh  = qh  + (size_t)2048 * 1024;
    unsigned short* vh  = kh  + (size_t)2048 * 1024;
    unsigned short* att = vh  + (size_t)2048 * 1024;   // [S][H*D]

    prep<<<2048, 256, 0, stream>>>(x, xb, Wq, Wk, Wv, Wo, Wtq, Wtk, Wtv, Wto);
    gemm_qkv<<<dim3(24, 32), 256, 0, stream>>>(xb, Wtq, Wtk, Wtv,
                                               qh, kh, vh, cs, sn);
    attn_kernel<<<(S_LEN * NH) / 4, 256, 0, stream>>>(qh, kh, vh, anc, att);
    gemm_out<<<dim3(16, 32), 256, 0, stream>>>(att, Wto, out);
}